// Round 3
// baseline (518.835 us; speedup 1.0000x reference)
//
#include <hip/hip_runtime.h>

// SAGEConv (mean aggr, root weight, L2 normalize), fp32 in/out.
// CSR counting-sort -> fused pull-aggregate (bf16 gather) + dual GEMM + L2norm.

constexpr int kNodes = 50000;
constexpr int kEdges = 800000;
constexpr int kF = 96;    // input features
constexpr int kH = 128;   // output features

// --- Kernel 0: pack x into bf16 (RNE), 8 features per thread -----------------
__global__ void __launch_bounds__(256)
cvt_kernel(const float* __restrict__ x, uint4* __restrict__ xh4) {
  const int i = blockIdx.x * 256 + threadIdx.x;
  constexpr int total = kNodes * kF / 8;  // 600000
  if (i >= total) return;
  const float4 v0 = reinterpret_cast<const float4*>(x)[i * 2];
  const float4 v1 = reinterpret_cast<const float4*>(x)[i * 2 + 1];
  auto pack2 = [](float a, float b) -> unsigned {
    unsigned ua = __float_as_uint(a), ub = __float_as_uint(b);
    ua = (ua + 0x7fffu + ((ua >> 16) & 1u)) >> 16;
    ub = (ub + 0x7fffu + ((ub >> 16) & 1u)) >> 16;
    return ua | (ub << 16);
  };
  uint4 o;
  o.x = pack2(v0.x, v0.y);
  o.y = pack2(v0.z, v0.w);
  o.z = pack2(v1.x, v1.y);
  o.w = pack2(v1.z, v1.w);
  xh4[i] = o;
}

// --- Kernel 1: integer degree ------------------------------------------------
__global__ void __launch_bounds__(256)
deg_kernel(const int* __restrict__ ei, int* __restrict__ degi) {
  int e = blockIdx.x * 256 + threadIdx.x;
  if (e >= kEdges) return;
  atomicAdd(&degi[ei[kEdges + e]], 1);
}

// --- Kernel 2: exclusive scan (single block, thread-serial + one block scan) -
__global__ void __launch_bounds__(1024)
scan_kernel(const int* __restrict__ degi, int* __restrict__ row_start,
            int* __restrict__ cursor) {
  constexpr int kPer = (kNodes + 1023) / 1024;  // 49
  const int tid = threadIdx.x;
  const int base = tid * kPer;
  int s = 0;
  for (int i = 0; i < kPer; ++i) {
    const int idx = base + i;
    if (idx < kNodes) s += degi[idx];
  }
  const int lane = tid & 63, wave = tid >> 6;
  int sc = s;
#pragma unroll
  for (int off = 1; off < 64; off <<= 1) {
    int t = __shfl_up(sc, off, 64);
    if (lane >= off) sc += t;
  }
  __shared__ int wsum[16];
  if (lane == 63) wsum[wave] = sc;
  __syncthreads();
  int woff = 0;
#pragma unroll
  for (int w = 0; w < 16; ++w) woff += (w < wave) ? wsum[w] : 0;
  int running = woff + sc - s;  // exclusive prefix for this thread's range
  for (int i = 0; i < kPer; ++i) {
    const int idx = base + i;
    if (idx < kNodes) {
      row_start[idx] = running;
      cursor[idx] = running;
      running += degi[idx];
    }
  }
  if (tid == 1023) row_start[kNodes] = running;  // == kEdges
}

// --- Kernel 3: fill CSR slots ------------------------------------------------
__global__ void __launch_bounds__(256)
fill_kernel(const int* __restrict__ ei, int* __restrict__ cursor,
            int* __restrict__ csr_src) {
  int e = blockIdx.x * 256 + threadIdx.x;
  if (e >= kEdges) return;
  const int dst = ei[kEdges + e];
  const int slot = atomicAdd(&cursor[dst], 1);
  csr_src[slot] = ei[e];
}

// --- Kernel 4: fused aggregate (bf16 gather) + dual GEMM + L2-normalize ------
// One wave per node. Gather: 4 edge-slots x 12 lanes x uint4 (8 bf16 feats).
// Lanes 48-63 prefetch the f32 self-row. GEMM: lane owns channels 2l, 2l+1.
__global__ void __launch_bounds__(1024)
fused_kernel(const float* __restrict__ x, const uint4* __restrict__ xh4,
             const int* __restrict__ row_start, const int* __restrict__ csr_src,
             const float* __restrict__ Wl, const float* __restrict__ bl,
             const float* __restrict__ Wr, float* __restrict__ out) {
  __shared__ float sWl[kF][kH];   // sW[f][h]; store-conflicts once, reads clean
  __shared__ float sWr[kF][kH];
  __shared__ float sAgg[16][kF];
  __shared__ float sXrow[16][kF];

  for (int i = threadIdx.x; i < kF * kH; i += 1024) {
    const int h = i / kF;
    const int f = i - h * kF;
    sWl[f][h] = Wl[i];   // W is [kH][kF] row-major
    sWr[f][h] = Wr[i];
  }
  __syncthreads();

  const int wave = threadIdx.x >> 6;
  const int lane = threadIdx.x & 63;
  const float2 b2 = reinterpret_cast<const float2*>(bl)[lane];

  const int node = blockIdx.x * 16 + wave;  // grid exact: 3125*16 = 50000
  const int s = row_start[node];
  const int e = row_start[node + 1];
  const int deg = e - s;

  // self-row prefetch into LDS by lanes 48..63 (24 float4 chunks)
  if (lane >= 48) {
    const int cc = lane - 48;  // 0..15
    const float4* xr4 = reinterpret_cast<const float4*>(x + (size_t)node * kF);
    float4* sx4 = reinterpret_cast<float4*>(&sXrow[wave][0]);
    sx4[cc] = xr4[cc];
    if (cc < 8) sx4[cc + 16] = xr4[cc + 16];
  }

  // gather: slot = lane/12 (0..3 active), chunk c = lane%12
  const int slot = lane / 12;
  const int c = lane % 12;
  const bool gactive = lane < 48;
  float a0 = 0.f, a1 = 0.f, a2 = 0.f, a3 = 0.f, a4 = 0.f, a5 = 0.f, a6 = 0.f, a7 = 0.f;

  const int nt = (deg + 3) >> 2;
#pragma unroll 2
  for (int t = 0; t < nt; ++t) {
    const int idx = s + (t << 2) + slot;
    if (gactive && idx < e) {
      const int src = csr_src[idx];
      const uint4 v = xh4[(size_t)src * 12 + c];
      a0 += __uint_as_float(v.x << 16);
      a1 += __uint_as_float(v.x & 0xffff0000u);
      a2 += __uint_as_float(v.y << 16);
      a3 += __uint_as_float(v.y & 0xffff0000u);
      a4 += __uint_as_float(v.z << 16);
      a5 += __uint_as_float(v.z & 0xffff0000u);
      a6 += __uint_as_float(v.w << 16);
      a7 += __uint_as_float(v.w & 0xffff0000u);
    }
  }
  // combine 4 slots -> lanes 0..11
  a0 += __shfl(a0, lane + 24, 64); a1 += __shfl(a1, lane + 24, 64);
  a2 += __shfl(a2, lane + 24, 64); a3 += __shfl(a3, lane + 24, 64);
  a4 += __shfl(a4, lane + 24, 64); a5 += __shfl(a5, lane + 24, 64);
  a6 += __shfl(a6, lane + 24, 64); a7 += __shfl(a7, lane + 24, 64);
  a0 += __shfl(a0, lane + 12, 64); a1 += __shfl(a1, lane + 12, 64);
  a2 += __shfl(a2, lane + 12, 64); a3 += __shfl(a3, lane + 12, 64);
  a4 += __shfl(a4, lane + 12, 64); a5 += __shfl(a5, lane + 12, 64);
  a6 += __shfl(a6, lane + 12, 64); a7 += __shfl(a7, lane + 12, 64);

  const float inv = 1.0f / fmaxf((float)deg, 1.0f);
  if (lane < 12) {
    float4* sa4 = reinterpret_cast<float4*>(&sAgg[wave][0]);
    sa4[c * 2]     = make_float4(a0 * inv, a1 * inv, a2 * inv, a3 * inv);
    sa4[c * 2 + 1] = make_float4(a4 * inv, a5 * inv, a6 * inv, a7 * inv);
  }
  // same-wave LDS write->read: compiler-inserted lgkmcnt ordering (as R2)

  float accA = b2.x, accB = b2.y;
#pragma unroll 4
  for (int f = 0; f < kF; ++f) {
    const float a  = sAgg[wave][f];
    const float xv = sXrow[wave][f];
    const float2 wl = reinterpret_cast<const float2*>(&sWl[f][0])[lane];
    const float2 wr = reinterpret_cast<const float2*>(&sWr[f][0])[lane];
    accA += a * wl.x + xv * wr.x;
    accB += a * wl.y + xv * wr.y;
  }

  float ss = accA * accA + accB * accB;
#pragma unroll
  for (int off = 32; off >= 1; off >>= 1) ss += __shfl_xor(ss, off, 64);
  const float scale = 1.0f / fmaxf(sqrtf(ss), 1e-12f);

  reinterpret_cast<float2*>(out + (size_t)node * kH)[lane] =
      make_float2(accA * scale, accB * scale);
}

extern "C" void kernel_launch(void* const* d_in, const int* in_sizes, int n_in,
                              void* d_out, int out_size, void* d_ws, size_t ws_size,
                              hipStream_t stream) {
  const int*   ei = (const int*)d_in[0];
  const float* x  = (const float*)d_in[1];
  const float* Wl = (const float*)d_in[2];
  const float* bl = (const float*)d_in[3];
  const float* Wr = (const float*)d_in[4];
  float* out = (float*)d_out;

  // ws layout: xh (bf16, 16B-aligned first), then int arrays
  uint4* xh4     = (uint4*)d_ws;                       // kNodes*kF*2 B = 9.6 MB
  int*  degi     = (int*)((char*)d_ws + (size_t)kNodes * kF * 2);
  int*  row_start = degi + kNodes;                     // [kNodes+1]
  int*  cursor    = row_start + kNodes + 1;            // [kNodes+1]
  int*  csr_src   = cursor + kNodes + 1;               // [kEdges]

  hipMemsetAsync(degi, 0, kNodes * sizeof(int), stream);

  constexpr int cvt_total = kNodes * kF / 8;
  cvt_kernel<<<(cvt_total + 255) / 256, 256, 0, stream>>>(x, xh4);

  const int eblocks = (kEdges + 255) / 256;
  deg_kernel<<<eblocks, 256, 0, stream>>>(ei, degi);
  scan_kernel<<<1, 1024, 0, stream>>>(degi, row_start, cursor);
  fill_kernel<<<eblocks, 256, 0, stream>>>(ei, cursor, csr_src);

  fused_kernel<<<kNodes / 16, 1024, 0, stream>>>(x, xh4, row_start, csr_src,
                                                 Wl, bl, Wr, out);
}

// Round 4
// 229.737 us; speedup vs baseline: 2.2584x; 2.2584x over previous
//
#include <hip/hip_runtime.h>

// SAGEConv (mean aggr, root weight, L2 normalize), fp32 in/out.
// CSR counting-sort (parallel scan) -> gather kernel (bf16) -> GEMM+norm kernel.

constexpr int kNodes = 50000;
constexpr int kEdges = 800000;
constexpr int kF = 96;    // input features
constexpr int kH = 128;   // output features
constexpr int kNB1 = (kNodes + 1023) / 1024;  // 49 scan blocks

__device__ __forceinline__ unsigned pack2_bf16(float a, float b) {
  unsigned ua = __float_as_uint(a), ub = __float_as_uint(b);
  ua = (ua + 0x7fffu + ((ua >> 16) & 1u)) >> 16;   // RNE
  ub = (ub + 0x7fffu + ((ub >> 16) & 1u)) >> 16;
  return ua | (ub << 16);
}
__device__ __forceinline__ float bf_lo(unsigned u) { return __uint_as_float(u << 16); }
__device__ __forceinline__ float bf_hi(unsigned u) { return __uint_as_float(u & 0xffff0000u); }

// --- pack x into bf16, 8 feats/thread ---------------------------------------
__global__ void __launch_bounds__(256)
cvt_kernel(const float* __restrict__ x, uint4* __restrict__ xh4) {
  const int i = blockIdx.x * 256 + threadIdx.x;
  constexpr int total = kNodes * kF / 8;
  if (i >= total) return;
  const float4 v0 = reinterpret_cast<const float4*>(x)[i * 2];
  const float4 v1 = reinterpret_cast<const float4*>(x)[i * 2 + 1];
  uint4 o;
  o.x = pack2_bf16(v0.x, v0.y);
  o.y = pack2_bf16(v0.z, v0.w);
  o.z = pack2_bf16(v1.x, v1.y);
  o.w = pack2_bf16(v1.z, v1.w);
  xh4[i] = o;
}

// --- degree ------------------------------------------------------------------
__global__ void __launch_bounds__(256)
deg_kernel(const int* __restrict__ ei, int* __restrict__ degi) {
  int e = blockIdx.x * 256 + threadIdx.x;
  if (e >= kEdges) return;
  atomicAdd(&degi[ei[kEdges + e]], 1);
}

// --- scan stage 1: per-block exclusive scan + block totals -------------------
__global__ void __launch_bounds__(1024)
scan1_kernel(const int* __restrict__ degi, int* __restrict__ row_start,
             int* __restrict__ btot) {
  const int tid = threadIdx.x;
  const int i = blockIdx.x * 1024 + tid;
  const int lane = tid & 63, wave = tid >> 6;
  const int v = (i < kNodes) ? degi[i] : 0;
  int sc = v;
#pragma unroll
  for (int off = 1; off < 64; off <<= 1) {
    int t = __shfl_up(sc, off, 64);
    if (lane >= off) sc += t;
  }
  __shared__ int wsum[16];
  if (lane == 63) wsum[wave] = sc;
  __syncthreads();
  int woff = 0;
#pragma unroll
  for (int w = 0; w < 16; ++w) woff += (w < wave) ? wsum[w] : 0;
  if (i < kNodes) row_start[i] = woff + sc - v;
  if (tid == 0) {
    int tot = 0;
#pragma unroll
    for (int w = 0; w < 16; ++w) tot += wsum[w];
    btot[blockIdx.x] = tot;
  }
}

// --- scan stage 2: scan the 49 block totals (one wave) -----------------------
__global__ void __launch_bounds__(64)
scan2_kernel(const int* __restrict__ btot, int* __restrict__ boff) {
  const int lane = threadIdx.x;
  int v = (lane < kNB1) ? btot[lane] : 0;
  int sc = v;
#pragma unroll
  for (int off = 1; off < 64; off <<= 1) {
    int t = __shfl_up(sc, off, 64);
    if (lane >= off) sc += t;
  }
  if (lane < kNB1) boff[lane] = sc - v;  // exclusive
}

// --- scan stage 3: add block offsets, init cursor, write sentinel ------------
__global__ void __launch_bounds__(256)
scan3_kernel(int* __restrict__ row_start, const int* __restrict__ boff,
             int* __restrict__ cursor) {
  const int i = blockIdx.x * 256 + threadIdx.x;
  if (i >= kNodes) return;
  const int val = row_start[i] + boff[i >> 10];
  row_start[i] = val;
  cursor[i] = val;
  if (i == 0) row_start[kNodes] = kEdges;
}

// --- fill CSR slots ----------------------------------------------------------
__global__ void __launch_bounds__(256)
fill_kernel(const int* __restrict__ ei, int* __restrict__ cursor,
            int* __restrict__ csr_src) {
  int e = blockIdx.x * 256 + threadIdx.x;
  if (e >= kEdges) return;
  const int dst = ei[kEdges + e];
  const int slot = atomicAdd(&cursor[dst], 1);
  csr_src[slot] = ei[e];
}

// --- gather: mean of neighbor bf16 rows -> aggh (bf16) -----------------------
// One wave per node (grid-stride). 4 edge-slots x 12 lanes x uint4 (8 feats).
__global__ void __launch_bounds__(256)
gather_kernel(const uint4* __restrict__ xh4, const int* __restrict__ row_start,
              const int* __restrict__ csr_src, uint4* __restrict__ aggh4) {
  const int wave = threadIdx.x >> 6, lane = threadIdx.x & 63;
  const int slot = lane / 12;
  const int c = lane % 12;
  const bool gactive = lane < 48;

  for (int node = blockIdx.x * 4 + wave; node < kNodes; node += gridDim.x * 4) {
    const int s = row_start[node];
    const int e = row_start[node + 1];
    const int deg = e - s;
    float a0 = 0.f, a1 = 0.f, a2 = 0.f, a3 = 0.f,
          a4 = 0.f, a5 = 0.f, a6 = 0.f, a7 = 0.f;
    const int nt = (deg + 3) >> 2;
    for (int t = 0; t < nt; ++t) {
      const int idx = s + (t << 2) + slot;
      if (gactive && idx < e) {
        const int src = csr_src[idx];
        const uint4 v = xh4[(size_t)src * 12 + c];
        a0 += bf_lo(v.x); a1 += bf_hi(v.x);
        a2 += bf_lo(v.y); a3 += bf_hi(v.y);
        a4 += bf_lo(v.z); a5 += bf_hi(v.z);
        a6 += bf_lo(v.w); a7 += bf_hi(v.w);
      }
    }
    // combine 4 slots -> lanes 0..11
    a0 += __shfl(a0, lane + 24, 64); a1 += __shfl(a1, lane + 24, 64);
    a2 += __shfl(a2, lane + 24, 64); a3 += __shfl(a3, lane + 24, 64);
    a4 += __shfl(a4, lane + 24, 64); a5 += __shfl(a5, lane + 24, 64);
    a6 += __shfl(a6, lane + 24, 64); a7 += __shfl(a7, lane + 24, 64);
    a0 += __shfl(a0, lane + 12, 64); a1 += __shfl(a1, lane + 12, 64);
    a2 += __shfl(a2, lane + 12, 64); a3 += __shfl(a3, lane + 12, 64);
    a4 += __shfl(a4, lane + 12, 64); a5 += __shfl(a5, lane + 12, 64);
    a6 += __shfl(a6, lane + 12, 64); a7 += __shfl(a7, lane + 12, 64);

    if (lane < 12) {
      const float inv = 1.0f / fmaxf((float)deg, 1.0f);
      uint4 o;
      o.x = pack2_bf16(a0 * inv, a1 * inv);
      o.y = pack2_bf16(a2 * inv, a3 * inv);
      o.z = pack2_bf16(a4 * inv, a5 * inv);
      o.w = pack2_bf16(a6 * inv, a7 * inv);
      aggh4[(size_t)node * 12 + c] = o;
    }
  }
}

// --- GEMM + L2-normalize -----------------------------------------------------
// Weights in LDS as bf16 channel-pairs: sW[f][l] = pack(W[l][f], W[l+64][f]).
// Lane-stride-1 reads -> conflict-free. One wave per node (grid-stride).
__global__ void __launch_bounds__(1024)
gemm_kernel(const float* __restrict__ x, const uint4* __restrict__ aggh4,
            const float* __restrict__ Wl, const float* __restrict__ bl,
            const float* __restrict__ Wr, float* __restrict__ out) {
  __shared__ unsigned sWl[kF][64];
  __shared__ unsigned sWr[kF][64];
  __shared__ float sX[16][kF];
  __shared__ unsigned sAg[16][kF / 2];

  for (int idx = threadIdx.x; idx < kF * 64; idx += 1024) {
    const int l = idx / kF, f = idx - l * kF;  // coalesced global reads
    sWl[f][l] = pack2_bf16(Wl[l * kF + f], Wl[(l + 64) * kF + f]);
    sWr[f][l] = pack2_bf16(Wr[l * kF + f], Wr[(l + 64) * kF + f]);
  }
  __syncthreads();

  const int wave = threadIdx.x >> 6, lane = threadIdx.x & 63;
  const float b0 = bl[lane], b1 = bl[lane + 64];

  for (int node = blockIdx.x * 16 + wave; node < kNodes; node += gridDim.x * 16) {
    if (lane < 24)
      reinterpret_cast<float4*>(&sX[wave][0])[lane] =
          reinterpret_cast<const float4*>(x)[(size_t)node * 24 + lane];
    else if (lane < 36)
      reinterpret_cast<uint4*>(&sAg[wave][0])[lane - 24] =
          aggh4[(size_t)node * 12 + (lane - 24)];
    // same-wave LDS RAW: compiler-inserted lgkmcnt ordering (proven R2/R3)

    float acc0 = b0, acc1 = b1;
#pragma unroll 4
    for (int j = 0; j < kF / 2; ++j) {
      const unsigned pa = sAg[wave][j];           // broadcast
      const float a0 = bf_lo(pa), a1 = bf_hi(pa);
      const float xv0 = sX[wave][2 * j], xv1 = sX[wave][2 * j + 1];
      const unsigned wl0 = sWl[2 * j][lane], wl1 = sWl[2 * j + 1][lane];
      const unsigned wr0 = sWr[2 * j][lane], wr1 = sWr[2 * j + 1][lane];
      acc0 += a0 * bf_lo(wl0) + a1 * bf_lo(wl1) + xv0 * bf_lo(wr0) + xv1 * bf_lo(wr1);
      acc1 += a0 * bf_hi(wl0) + a1 * bf_hi(wl1) + xv0 * bf_hi(wr0) + xv1 * bf_hi(wr1);
    }

    float ss = acc0 * acc0 + acc1 * acc1;
#pragma unroll
    for (int off = 32; off >= 1; off >>= 1) ss += __shfl_xor(ss, off, 64);
    const float scale = 1.0f / fmaxf(sqrtf(ss), 1e-12f);
    out[(size_t)node * kH + lane] = acc0 * scale;
    out[(size_t)node * kH + lane + 64] = acc1 * scale;
  }
}

extern "C" void kernel_launch(void* const* d_in, const int* in_sizes, int n_in,
                              void* d_out, int out_size, void* d_ws, size_t ws_size,
                              hipStream_t stream) {
  const int*   ei = (const int*)d_in[0];
  const float* x  = (const float*)d_in[1];
  const float* Wl = (const float*)d_in[2];
  const float* bl = (const float*)d_in[3];
  const float* Wr = (const float*)d_in[4];
  float* out = (float*)d_out;

  char* ws = (char*)d_ws;
  uint4* xh4   = (uint4*)ws;                                   // 9.6 MB
  uint4* aggh4 = (uint4*)(ws + (size_t)kNodes * kF * 2);       // 9.6 MB
  int* degi      = (int*)(ws + (size_t)kNodes * kF * 4);
  int* row_start = degi + kNodes;           // [kNodes+1]
  int* cursor    = row_start + kNodes + 1;  // [kNodes]
  int* btot      = cursor + kNodes;         // [kNB1]
  int* boff      = btot + kNB1;             // [kNB1]
  int* csr_src   = boff + kNB1;             // [kEdges]

  hipMemsetAsync(degi, 0, kNodes * sizeof(int), stream);

  constexpr int cvt_total = kNodes * kF / 8;
  cvt_kernel<<<(cvt_total + 255) / 256, 256, 0, stream>>>(x, xh4);

  const int eblocks = (kEdges + 255) / 256;
  deg_kernel<<<eblocks, 256, 0, stream>>>(ei, degi);
  scan1_kernel<<<kNB1, 1024, 0, stream>>>(degi, row_start, btot);
  scan2_kernel<<<1, 64, 0, stream>>>(btot, boff);
  scan3_kernel<<<(kNodes + 255) / 256, 256, 0, stream>>>(row_start, boff, cursor);
  fill_kernel<<<eblocks, 256, 0, stream>>>(ei, cursor, csr_src);

  gather_kernel<<<3125, 256, 0, stream>>>(xh4, row_start, csr_src, aggh4);
  gemm_kernel<<<512, 1024, 0, stream>>>(x, aggh4, Wl, bl, Wr, out);
}

// Round 5
// 177.577 us; speedup vs baseline: 2.9218x; 1.2937x over previous
//
#include <hip/hip_runtime.h>

// SAGEConv (mean aggr, root weight, L2 normalize), fp32 in/out.
// CSR counting-sort -> gather (bf16) -> MFMA GEMM over concat K=192 + L2norm.

typedef __attribute__((ext_vector_type(8))) short short8;   // 8 bf16 = 4 VGPRs
typedef __attribute__((ext_vector_type(4))) float floatx4;  // MFMA acc

constexpr int kNodes = 50000;
constexpr int kEdges = 800000;
constexpr int kF = 96;    // input features
constexpr int kH = 128;   // output features
constexpr int kNB1 = (kNodes + 1023) / 1024;  // 49 scan blocks

__device__ __forceinline__ unsigned pack2_bf16(float a, float b) {
  unsigned ua = __float_as_uint(a), ub = __float_as_uint(b);
  ua = (ua + 0x7fffu + ((ua >> 16) & 1u)) >> 16;   // RNE
  ub = (ub + 0x7fffu + ((ub >> 16) & 1u)) >> 16;
  return ua | (ub << 16);
}
__device__ __forceinline__ float bf_lo(unsigned u) { return __uint_as_float(u << 16); }
__device__ __forceinline__ float bf_hi(unsigned u) { return __uint_as_float(u & 0xffff0000u); }

// --- pack x into bf16, 8 feats/thread ---------------------------------------
__global__ void __launch_bounds__(256)
cvt_kernel(const float* __restrict__ x, uint4* __restrict__ xh4) {
  const int i = blockIdx.x * 256 + threadIdx.x;
  constexpr int total = kNodes * kF / 8;
  if (i >= total) return;
  const float4 v0 = reinterpret_cast<const float4*>(x)[i * 2];
  const float4 v1 = reinterpret_cast<const float4*>(x)[i * 2 + 1];
  uint4 o;
  o.x = pack2_bf16(v0.x, v0.y);
  o.y = pack2_bf16(v0.z, v0.w);
  o.z = pack2_bf16(v1.x, v1.y);
  o.w = pack2_bf16(v1.z, v1.w);
  xh4[i] = o;
}

// --- pack W = [Wl | Wr] into bf16 [128][192] ---------------------------------
__global__ void __launch_bounds__(256)
wcvt_kernel(const float* __restrict__ Wl, const float* __restrict__ Wr,
            uint4* __restrict__ wh4) {
  const int i = blockIdx.x * 256 + threadIdx.x;
  constexpr int total = kH * 192 / 8;  // 3072
  if (i >= total) return;
  const int row = i / 24, chunk = i % 24;
  const float* src = (chunk < 12) ? (Wl + (size_t)row * kF + chunk * 8)
                                  : (Wr + (size_t)row * kF + (chunk - 12) * 8);
  const float4 v0 = reinterpret_cast<const float4*>(src)[0];
  const float4 v1 = reinterpret_cast<const float4*>(src)[1];
  uint4 o;
  o.x = pack2_bf16(v0.x, v0.y);
  o.y = pack2_bf16(v0.z, v0.w);
  o.z = pack2_bf16(v1.x, v1.y);
  o.w = pack2_bf16(v1.z, v1.w);
  wh4[i] = o;
}

// --- degree ------------------------------------------------------------------
__global__ void __launch_bounds__(256)
deg_kernel(const int* __restrict__ ei, int* __restrict__ degi) {
  int e = blockIdx.x * 256 + threadIdx.x;
  if (e >= kEdges) return;
  atomicAdd(&degi[ei[kEdges + e]], 1);
}

// --- scan stage 1: per-block exclusive scan + block totals -------------------
__global__ void __launch_bounds__(1024)
scan1_kernel(const int* __restrict__ degi, int* __restrict__ row_start,
             int* __restrict__ btot) {
  const int tid = threadIdx.x;
  const int i = blockIdx.x * 1024 + tid;
  const int lane = tid & 63, wave = tid >> 6;
  const int v = (i < kNodes) ? degi[i] : 0;
  int sc = v;
#pragma unroll
  for (int off = 1; off < 64; off <<= 1) {
    int t = __shfl_up(sc, off, 64);
    if (lane >= off) sc += t;
  }
  __shared__ int wsum[16];
  if (lane == 63) wsum[wave] = sc;
  __syncthreads();
  int woff = 0;
#pragma unroll
  for (int w = 0; w < 16; ++w) woff += (w < wave) ? wsum[w] : 0;
  if (i < kNodes) row_start[i] = woff + sc - v;
  if (tid == 0) {
    int tot = 0;
#pragma unroll
    for (int w = 0; w < 16; ++w) tot += wsum[w];
    btot[blockIdx.x] = tot;
  }
}

// --- scan stage 2: scan the 49 block totals (one wave) -----------------------
__global__ void __launch_bounds__(64)
scan2_kernel(const int* __restrict__ btot, int* __restrict__ boff) {
  const int lane = threadIdx.x;
  int v = (lane < kNB1) ? btot[lane] : 0;
  int sc = v;
#pragma unroll
  for (int off = 1; off < 64; off <<= 1) {
    int t = __shfl_up(sc, off, 64);
    if (lane >= off) sc += t;
  }
  if (lane < kNB1) boff[lane] = sc - v;  // exclusive
}

// --- scan stage 3: add block offsets, init cursor, write sentinel ------------
__global__ void __launch_bounds__(256)
scan3_kernel(int* __restrict__ row_start, const int* __restrict__ boff,
             int* __restrict__ cursor) {
  const int i = blockIdx.x * 256 + threadIdx.x;
  if (i >= kNodes) return;
  const int val = row_start[i] + boff[i >> 10];
  row_start[i] = val;
  cursor[i] = val;
  if (i == 0) row_start[kNodes] = kEdges;
}

// --- fill CSR slots ----------------------------------------------------------
__global__ void __launch_bounds__(256)
fill_kernel(const int* __restrict__ ei, int* __restrict__ cursor,
            int* __restrict__ csr_src) {
  int e = blockIdx.x * 256 + threadIdx.x;
  if (e >= kEdges) return;
  const int dst = ei[kEdges + e];
  const int slot = atomicAdd(&cursor[dst], 1);
  csr_src[slot] = ei[e];
}

// --- gather: mean of neighbor bf16 rows -> aggh (bf16) -----------------------
// One wave per node (grid-stride). 4 edge-slots x 12 lanes x uint4 (8 feats).
__global__ void __launch_bounds__(256)
gather_kernel(const uint4* __restrict__ xh4, const int* __restrict__ row_start,
              const int* __restrict__ csr_src, uint4* __restrict__ aggh4) {
  const int wave = threadIdx.x >> 6, lane = threadIdx.x & 63;
  const int slot = lane / 12;
  const int c = lane % 12;
  const bool gactive = lane < 48;

  for (int node = blockIdx.x * 4 + wave; node < kNodes; node += gridDim.x * 4) {
    const int s = row_start[node];
    const int e = row_start[node + 1];
    const int deg = e - s;
    float a0 = 0.f, a1 = 0.f, a2 = 0.f, a3 = 0.f,
          a4 = 0.f, a5 = 0.f, a6 = 0.f, a7 = 0.f;
    const int nt = (deg + 3) >> 2;
    for (int t = 0; t < nt; ++t) {
      const int idx = s + (t << 2) + slot;
      if (gactive && idx < e) {
        const int src = csr_src[idx];
        const uint4 v = xh4[(size_t)src * 12 + c];
        a0 += bf_lo(v.x); a1 += bf_hi(v.x);
        a2 += bf_lo(v.y); a3 += bf_hi(v.y);
        a4 += bf_lo(v.z); a5 += bf_hi(v.z);
        a6 += bf_lo(v.w); a7 += bf_hi(v.w);
      }
    }
    // combine 4 slots -> lanes 0..11
    a0 += __shfl(a0, lane + 24, 64); a1 += __shfl(a1, lane + 24, 64);
    a2 += __shfl(a2, lane + 24, 64); a3 += __shfl(a3, lane + 24, 64);
    a4 += __shfl(a4, lane + 24, 64); a5 += __shfl(a5, lane + 24, 64);
    a6 += __shfl(a6, lane + 24, 64); a7 += __shfl(a7, lane + 24, 64);
    a0 += __shfl(a0, lane + 12, 64); a1 += __shfl(a1, lane + 12, 64);
    a2 += __shfl(a2, lane + 12, 64); a3 += __shfl(a3, lane + 12, 64);
    a4 += __shfl(a4, lane + 12, 64); a5 += __shfl(a5, lane + 12, 64);
    a6 += __shfl(a6, lane + 12, 64); a7 += __shfl(a7, lane + 12, 64);

    if (lane < 12) {
      const float inv = 1.0f / fmaxf((float)deg, 1.0f);
      uint4 o;
      o.x = pack2_bf16(a0 * inv, a1 * inv);
      o.y = pack2_bf16(a2 * inv, a3 * inv);
      o.z = pack2_bf16(a4 * inv, a5 * inv);
      o.w = pack2_bf16(a6 * inv, a7 * inv);
      aggh4[(size_t)node * 12 + c] = o;
    }
  }
}

// --- MFMA GEMM + bias + L2-normalize -----------------------------------------
// C[50000x128] = [agg | x]_bf16 @ Wh^T + b, row-normalized.
// One wave per 16-node tile, 8 channel-group acc frags, K=192 in 6 steps.
// A-frag: row=lane&15, k=(lane>>4)*8+j  -> exactly one uint4 of the packed row.
// B-frag: b[j] = W[col][k] with col=lane&15(+16cg), same k-slice -> one uint4 of Wh.
// D: col=lane&15, row=(lane>>4)*4+reg  (m89-verified mapping).
__global__ void __launch_bounds__(256)
mfma_kernel(const uint4* __restrict__ xh4, const uint4* __restrict__ aggh4,
            const uint4* __restrict__ wh4, const float* __restrict__ bl,
            float* __restrict__ out) {
  const int wave = threadIdx.x >> 6, lane = threadIdx.x & 63;
  const int tile = blockIdx.x * 4 + wave;
  if (tile >= kNodes / 16) return;  // 3125 tiles exact
  const int base = tile * 16;
  const int r = lane & 15, q = lane >> 4;

  const short8* aggS = reinterpret_cast<const short8*>(aggh4);
  const short8* xhS  = reinterpret_cast<const short8*>(xh4);
  const short8* whS  = reinterpret_cast<const short8*>(wh4);

  floatx4 acc[8] = {};
#pragma unroll
  for (int ks = 0; ks < 6; ++ks) {
    const short8* Ab = (ks < 3) ? aggS : xhS;
    const int chunk = (ks < 3 ? ks * 4 : (ks - 3) * 4) + q;
    const short8 a = Ab[(size_t)(base + r) * 12 + chunk];
#pragma unroll
    for (int cg = 0; cg < 8; ++cg) {
      const short8 b = whS[(cg * 16 + r) * 24 + ks * 4 + q];
      acc[cg] = __builtin_amdgcn_mfma_f32_16x16x32_bf16(a, b, acc[cg], 0, 0, 0);
    }
  }

  // bias + sum-of-squares per output row (row = q*4 + reg)
  float p0 = 0.f, p1 = 0.f, p2 = 0.f, p3 = 0.f;
#pragma unroll
  for (int cg = 0; cg < 8; ++cg) {
    const float bb = bl[cg * 16 + r];
    acc[cg][0] += bb; acc[cg][1] += bb; acc[cg][2] += bb; acc[cg][3] += bb;
    p0 += acc[cg][0] * acc[cg][0];
    p1 += acc[cg][1] * acc[cg][1];
    p2 += acc[cg][2] * acc[cg][2];
    p3 += acc[cg][3] * acc[cg][3];
  }
  // reduce across the 16 lanes of this lane-group (offsets 1..8 stay in-group)
#pragma unroll
  for (int off = 1; off < 16; off <<= 1) {
    p0 += __shfl_xor(p0, off, 64);
    p1 += __shfl_xor(p1, off, 64);
    p2 += __shfl_xor(p2, off, 64);
    p3 += __shfl_xor(p3, off, 64);
  }
  const float s0 = 1.0f / fmaxf(sqrtf(p0), 1e-12f);
  const float s1 = 1.0f / fmaxf(sqrtf(p1), 1e-12f);
  const float s2 = 1.0f / fmaxf(sqrtf(p2), 1e-12f);
  const float s3 = 1.0f / fmaxf(sqrtf(p3), 1e-12f);

#pragma unroll
  for (int cg = 0; cg < 8; ++cg) {
    const int col = cg * 16 + r;
    float* o = out + (size_t)(base + q * 4) * kH + col;
    o[0 * kH] = acc[cg][0] * s0;
    o[1 * kH] = acc[cg][1] * s1;
    o[2 * kH] = acc[cg][2] * s2;
    o[3 * kH] = acc[cg][3] * s3;
  }
}

extern "C" void kernel_launch(void* const* d_in, const int* in_sizes, int n_in,
                              void* d_out, int out_size, void* d_ws, size_t ws_size,
                              hipStream_t stream) {
  const int*   ei = (const int*)d_in[0];
  const float* x  = (const float*)d_in[1];
  const float* Wl = (const float*)d_in[2];
  const float* bl = (const float*)d_in[3];
  const float* Wr = (const float*)d_in[4];
  float* out = (float*)d_out;

  char* ws = (char*)d_ws;
  uint4* xh4   = (uint4*)ws;                                   // 9.6 MB
  uint4* aggh4 = (uint4*)(ws + (size_t)kNodes * kF * 2);       // 9.6 MB
  uint4* wh4   = (uint4*)(ws + (size_t)kNodes * kF * 4);       // 49 KB
  int* degi      = (int*)(ws + (size_t)kNodes * kF * 4 + kH * 192 * 2);
  int* row_start = degi + kNodes;           // [kNodes+1]
  int* cursor    = row_start + kNodes + 1;  // [kNodes]
  int* btot      = cursor + kNodes;         // [kNB1]
  int* boff      = btot + kNB1;             // [kNB1]
  int* csr_src   = boff + kNB1;             // [kEdges]

  hipMemsetAsync(degi, 0, kNodes * sizeof(int), stream);

  constexpr int cvt_total = kNodes * kF / 8;
  cvt_kernel<<<(cvt_total + 255) / 256, 256, 0, stream>>>(x, xh4);
  wcvt_kernel<<<(kH * 192 / 8 + 255) / 256, 256, 0, stream>>>(Wl, Wr, wh4);

  const int eblocks = (kEdges + 255) / 256;
  deg_kernel<<<eblocks, 256, 0, stream>>>(ei, degi);
  scan1_kernel<<<kNB1, 1024, 0, stream>>>(degi, row_start, btot);
  scan2_kernel<<<1, 64, 0, stream>>>(btot, boff);
  scan3_kernel<<<(kNodes + 255) / 256, 256, 0, stream>>>(row_start, boff, cursor);
  fill_kernel<<<eblocks, 256, 0, stream>>>(ei, cursor, csr_src);

  gather_kernel<<<3125, 256, 0, stream>>>(xh4, row_start, csr_src, aggh4);

  constexpr int tiles = kNodes / 16;                 // 3125
  mfma_kernel<<<(tiles + 3) / 4, 256, 0, stream>>>(xh4, aggh4, wh4, bl, out);
}

// Round 6
// 170.801 us; speedup vs baseline: 3.0377x; 1.0397x over previous
//
#include <hip/hip_runtime.h>

// SAGEConv (mean aggr, root weight, L2 normalize), fp32 in/out.
// CSR counting-sort -> gather (bf16) -> MFMA GEMM over concat K=192 + L2norm.
// R6: ILP-4 fill/deg (hide atomic-return latency), fused prep + fused scan23.

typedef __attribute__((ext_vector_type(8))) short short8;   // 8 bf16 = 4 VGPRs
typedef __attribute__((ext_vector_type(4))) float floatx4;  // MFMA acc

constexpr int kNodes = 50000;
constexpr int kEdges = 800000;
constexpr int kF = 96;    // input features
constexpr int kH = 128;   // output features
constexpr int kNB1 = (kNodes + 1023) / 1024;  // 49 scan blocks
constexpr int kEQ = kEdges / 4;               // 200000 (exact)

__device__ __forceinline__ unsigned pack2_bf16(float a, float b) {
  unsigned ua = __float_as_uint(a), ub = __float_as_uint(b);
  ua = (ua + 0x7fffu + ((ua >> 16) & 1u)) >> 16;   // RNE
  ub = (ub + 0x7fffu + ((ub >> 16) & 1u)) >> 16;
  return ua | (ub << 16);
}
__device__ __forceinline__ float bf_lo(unsigned u) { return __uint_as_float(u << 16); }
__device__ __forceinline__ float bf_hi(unsigned u) { return __uint_as_float(u & 0xffff0000u); }

// --- prep: pack x -> bf16, pack W=[Wl|Wr] -> bf16, zero degi ------------------
__global__ void __launch_bounds__(256)
prep_kernel(const float* __restrict__ x, const float* __restrict__ Wl,
            const float* __restrict__ Wr, uint4* __restrict__ xh4,
            uint4* __restrict__ wh4, uint4* __restrict__ degi4) {
  constexpr int kCvt = kNodes * kF / 8;     // 600000
  constexpr int kWcvt = kH * 192 / 8;       // 3072
  constexpr int kZero = kNodes / 4;         // 12500
  const int i = blockIdx.x * 256 + threadIdx.x;
  if (i < kCvt) {
    const float4 v0 = reinterpret_cast<const float4*>(x)[i * 2];
    const float4 v1 = reinterpret_cast<const float4*>(x)[i * 2 + 1];
    uint4 o;
    o.x = pack2_bf16(v0.x, v0.y);
    o.y = pack2_bf16(v0.z, v0.w);
    o.z = pack2_bf16(v1.x, v1.y);
    o.w = pack2_bf16(v1.z, v1.w);
    xh4[i] = o;
  } else if (i < kCvt + kWcvt) {
    const int j = i - kCvt;
    const int row = j / 24, chunk = j % 24;
    const float* src = (chunk < 12) ? (Wl + (size_t)row * kF + chunk * 8)
                                    : (Wr + (size_t)row * kF + (chunk - 12) * 8);
    const float4 v0 = reinterpret_cast<const float4*>(src)[0];
    const float4 v1 = reinterpret_cast<const float4*>(src)[1];
    uint4 o;
    o.x = pack2_bf16(v0.x, v0.y);
    o.y = pack2_bf16(v0.z, v0.w);
    o.z = pack2_bf16(v1.x, v1.y);
    o.w = pack2_bf16(v1.z, v1.w);
    wh4[j] = o;
  } else if (i < kCvt + kWcvt + kZero) {
    degi4[i - kCvt - kWcvt] = make_uint4(0, 0, 0, 0);
  }
}

// --- degree, 4 edges/thread (fire-and-forget atomics) ------------------------
__global__ void __launch_bounds__(256)
deg_kernel(const int* __restrict__ ei, int* __restrict__ degi) {
  const int i = blockIdx.x * 256 + threadIdx.x;
  if (i >= kEQ) return;
  const int d0 = ei[kEdges + i];
  const int d1 = ei[kEdges + i + kEQ];
  const int d2 = ei[kEdges + i + 2 * kEQ];
  const int d3 = ei[kEdges + i + 3 * kEQ];
  atomicAdd(&degi[d0], 1);
  atomicAdd(&degi[d1], 1);
  atomicAdd(&degi[d2], 1);
  atomicAdd(&degi[d3], 1);
}

// --- scan stage 1: per-block exclusive scan + block totals -------------------
__global__ void __launch_bounds__(1024)
scan1_kernel(const int* __restrict__ degi, int* __restrict__ row_start,
             int* __restrict__ btot) {
  const int tid = threadIdx.x;
  const int i = blockIdx.x * 1024 + tid;
  const int lane = tid & 63, wave = tid >> 6;
  const int v = (i < kNodes) ? degi[i] : 0;
  int sc = v;
#pragma unroll
  for (int off = 1; off < 64; off <<= 1) {
    int t = __shfl_up(sc, off, 64);
    if (lane >= off) sc += t;
  }
  __shared__ int wsum[16];
  if (lane == 63) wsum[wave] = sc;
  __syncthreads();
  int woff = 0;
#pragma unroll
  for (int w = 0; w < 16; ++w) woff += (w < wave) ? wsum[w] : 0;
  if (i < kNodes) row_start[i] = woff + sc - v;
  if (tid == 0) {
    int tot = 0;
#pragma unroll
    for (int w = 0; w < 16; ++w) tot += wsum[w];
    btot[blockIdx.x] = tot;
  }
}

// --- scan stage 2+3 fused: each block wave-scans the 49 totals, applies ------
__global__ void __launch_bounds__(256)
scan23_kernel(int* __restrict__ row_start, const int* __restrict__ btot,
              int* __restrict__ cursor) {
  __shared__ int sBoff[kNB1];
  const int tid = threadIdx.x;
  if (tid < 64) {
    const int v = (tid < kNB1) ? btot[tid] : 0;
    int sc = v;
#pragma unroll
    for (int off = 1; off < 64; off <<= 1) {
      int t = __shfl_up(sc, off, 64);
      if (tid >= off) sc += t;
    }
    if (tid < kNB1) sBoff[tid] = sc - v;  // exclusive
  }
  __syncthreads();
  const int i = blockIdx.x * 256 + tid;
  if (i < kNodes) {
    const int val = row_start[i] + sBoff[i >> 10];
    row_start[i] = val;
    cursor[i] = val;
  }
  if (i == 0) row_start[kNodes] = kEdges;
}

// --- fill CSR slots, 4 edges/thread (ILP hides atomic-return latency) --------
__global__ void __launch_bounds__(256)
fill_kernel(const int* __restrict__ ei, int* __restrict__ cursor,
            int* __restrict__ csr_src) {
  const int i = blockIdx.x * 256 + threadIdx.x;
  if (i >= kEQ) return;
  const int s0 = ei[i];
  const int s1 = ei[i + kEQ];
  const int s2 = ei[i + 2 * kEQ];
  const int s3 = ei[i + 3 * kEQ];
  const int d0 = ei[kEdges + i];
  const int d1 = ei[kEdges + i + kEQ];
  const int d2 = ei[kEdges + i + 2 * kEQ];
  const int d3 = ei[kEdges + i + 3 * kEQ];
  const int p0 = atomicAdd(&cursor[d0], 1);
  const int p1 = atomicAdd(&cursor[d1], 1);
  const int p2 = atomicAdd(&cursor[d2], 1);
  const int p3 = atomicAdd(&cursor[d3], 1);
  csr_src[p0] = s0;
  csr_src[p1] = s1;
  csr_src[p2] = s2;
  csr_src[p3] = s3;
}

// --- gather: mean of neighbor bf16 rows -> aggh (bf16) -----------------------
// One wave per node (grid-stride). 4 edge-slots x 12 lanes x uint4 (8 feats).
__global__ void __launch_bounds__(256)
gather_kernel(const uint4* __restrict__ xh4, const int* __restrict__ row_start,
              const int* __restrict__ csr_src, uint4* __restrict__ aggh4) {
  const int wave = threadIdx.x >> 6, lane = threadIdx.x & 63;
  const int slot = lane / 12;
  const int c = lane % 12;
  const bool gactive = lane < 48;

  for (int node = blockIdx.x * 4 + wave; node < kNodes; node += gridDim.x * 4) {
    const int s = row_start[node];
    const int e = row_start[node + 1];
    const int deg = e - s;
    float a0 = 0.f, a1 = 0.f, a2 = 0.f, a3 = 0.f,
          a4 = 0.f, a5 = 0.f, a6 = 0.f, a7 = 0.f;
    const int nt = (deg + 3) >> 2;
    for (int t = 0; t < nt; ++t) {
      const int idx = s + (t << 2) + slot;
      if (gactive && idx < e) {
        const int src = csr_src[idx];
        const uint4 v = xh4[(size_t)src * 12 + c];
        a0 += bf_lo(v.x); a1 += bf_hi(v.x);
        a2 += bf_lo(v.y); a3 += bf_hi(v.y);
        a4 += bf_lo(v.z); a5 += bf_hi(v.z);
        a6 += bf_lo(v.w); a7 += bf_hi(v.w);
      }
    }
    // combine 4 slots -> lanes 0..11
    a0 += __shfl(a0, lane + 24, 64); a1 += __shfl(a1, lane + 24, 64);
    a2 += __shfl(a2, lane + 24, 64); a3 += __shfl(a3, lane + 24, 64);
    a4 += __shfl(a4, lane + 24, 64); a5 += __shfl(a5, lane + 24, 64);
    a6 += __shfl(a6, lane + 24, 64); a7 += __shfl(a7, lane + 24, 64);
    a0 += __shfl(a0, lane + 12, 64); a1 += __shfl(a1, lane + 12, 64);
    a2 += __shfl(a2, lane + 12, 64); a3 += __shfl(a3, lane + 12, 64);
    a4 += __shfl(a4, lane + 12, 64); a5 += __shfl(a5, lane + 12, 64);
    a6 += __shfl(a6, lane + 12, 64); a7 += __shfl(a7, lane + 12, 64);

    if (lane < 12) {
      const float inv = 1.0f / fmaxf((float)deg, 1.0f);
      uint4 o;
      o.x = pack2_bf16(a0 * inv, a1 * inv);
      o.y = pack2_bf16(a2 * inv, a3 * inv);
      o.z = pack2_bf16(a4 * inv, a5 * inv);
      o.w = pack2_bf16(a6 * inv, a7 * inv);
      aggh4[(size_t)node * 12 + c] = o;
    }
  }
}

// --- MFMA GEMM + bias + L2-normalize -----------------------------------------
// C[50000x128] = [agg | x]_bf16 @ Wh^T + b, row-normalized.
// A-frag: row=lane&15, k=(lane>>4)*8+j -> one uint4 of the packed row.
// D: col=lane&15, row=(lane>>4)*4+reg  (m89-verified mapping).
__global__ void __launch_bounds__(256)
mfma_kernel(const uint4* __restrict__ xh4, const uint4* __restrict__ aggh4,
            const uint4* __restrict__ wh4, const float* __restrict__ bl,
            float* __restrict__ out) {
  const int wave = threadIdx.x >> 6, lane = threadIdx.x & 63;
  const int tile = blockIdx.x * 4 + wave;
  if (tile >= kNodes / 16) return;  // 3125 tiles exact
  const int base = tile * 16;
  const int r = lane & 15, q = lane >> 4;

  const short8* aggS = reinterpret_cast<const short8*>(aggh4);
  const short8* xhS  = reinterpret_cast<const short8*>(xh4);
  const short8* whS  = reinterpret_cast<const short8*>(wh4);

  floatx4 acc[8] = {};
#pragma unroll
  for (int ks = 0; ks < 6; ++ks) {
    const short8* Ab = (ks < 3) ? aggS : xhS;
    const int chunk = (ks < 3 ? ks * 4 : (ks - 3) * 4) + q;
    const short8 a = Ab[(size_t)(base + r) * 12 + chunk];
#pragma unroll
    for (int cg = 0; cg < 8; ++cg) {
      const short8 b = whS[(cg * 16 + r) * 24 + ks * 4 + q];
      acc[cg] = __builtin_amdgcn_mfma_f32_16x16x32_bf16(a, b, acc[cg], 0, 0, 0);
    }
  }

  float p0 = 0.f, p1 = 0.f, p2 = 0.f, p3 = 0.f;
#pragma unroll
  for (int cg = 0; cg < 8; ++cg) {
    const float bb = bl[cg * 16 + r];
    acc[cg][0] += bb; acc[cg][1] += bb; acc[cg][2] += bb; acc[cg][3] += bb;
    p0 += acc[cg][0] * acc[cg][0];
    p1 += acc[cg][1] * acc[cg][1];
    p2 += acc[cg][2] * acc[cg][2];
    p3 += acc[cg][3] * acc[cg][3];
  }
#pragma unroll
  for (int off = 1; off < 16; off <<= 1) {
    p0 += __shfl_xor(p0, off, 64);
    p1 += __shfl_xor(p1, off, 64);
    p2 += __shfl_xor(p2, off, 64);
    p3 += __shfl_xor(p3, off, 64);
  }
  const float s0 = 1.0f / fmaxf(sqrtf(p0), 1e-12f);
  const float s1 = 1.0f / fmaxf(sqrtf(p1), 1e-12f);
  const float s2 = 1.0f / fmaxf(sqrtf(p2), 1e-12f);
  const float s3 = 1.0f / fmaxf(sqrtf(p3), 1e-12f);

#pragma unroll
  for (int cg = 0; cg < 8; ++cg) {
    const int col = cg * 16 + r;
    float* o = out + (size_t)(base + q * 4) * kH + col;
    o[0 * kH] = acc[cg][0] * s0;
    o[1 * kH] = acc[cg][1] * s1;
    o[2 * kH] = acc[cg][2] * s2;
    o[3 * kH] = acc[cg][3] * s3;
  }
}

extern "C" void kernel_launch(void* const* d_in, const int* in_sizes, int n_in,
                              void* d_out, int out_size, void* d_ws, size_t ws_size,
                              hipStream_t stream) {
  const int*   ei = (const int*)d_in[0];
  const float* x  = (const float*)d_in[1];
  const float* Wl = (const float*)d_in[2];
  const float* bl = (const float*)d_in[3];
  const float* Wr = (const float*)d_in[4];
  float* out = (float*)d_out;

  char* ws = (char*)d_ws;
  uint4* xh4   = (uint4*)ws;                                   // 9.6 MB
  uint4* aggh4 = (uint4*)(ws + (size_t)kNodes * kF * 2);       // 9.6 MB
  uint4* wh4   = (uint4*)(ws + (size_t)kNodes * kF * 4);       // 49 KB
  int* degi      = (int*)(ws + (size_t)kNodes * kF * 4 + kH * 192 * 2);
  int* row_start = degi + kNodes;           // [kNodes+1]
  int* cursor    = row_start + kNodes + 1;  // [kNodes]
  int* btot      = cursor + kNodes;         // [kNB1]
  int* csr_src   = btot + kNB1;             // [kEdges]

  constexpr int kPrepTotal = kNodes * kF / 8 + kH * 192 / 8 + kNodes / 4;
  prep_kernel<<<(kPrepTotal + 255) / 256, 256, 0, stream>>>(x, Wl, Wr, xh4, wh4,
                                                            (uint4*)degi);

  const int qblocks = (kEQ + 255) / 256;  // 782
  deg_kernel<<<qblocks, 256, 0, stream>>>(ei, degi);
  scan1_kernel<<<kNB1, 1024, 0, stream>>>(degi, row_start, btot);
  scan23_kernel<<<(kNodes + 255) / 256, 256, 0, stream>>>(row_start, btot, cursor);
  fill_kernel<<<qblocks, 256, 0, stream>>>(ei, cursor, csr_src);

  gather_kernel<<<3125, 256, 0, stream>>>(xh4, row_start, csr_src, aggh4);

  constexpr int tiles = kNodes / 16;                 // 3125
  mfma_kernel<<<(tiles + 3) / 4, 256, 0, stream>>>(xh4, aggh4, wh4, bl, out);
}